// Round 10
// baseline (213.933 us; speedup 1.0000x reference)
//
#include <hip/hip_runtime.h>
#include <math.h>

// Problem constants (match reference)
constexpr int C   = 6;
constexpr int NR  = 2048;
constexpr int NC  = 2048;
constexpr int KS  = 10;
constexpr int PAD = 4;              // top/left circular halo

// R11 (= R10 + halo addressing fix): R2 structure + register->LDS dedup of the
// window reads (no DMA).
// Evidence R2/R4/R7/R8/R9: effective BW pinned ~2.2-2.6 TB/s regardless of
// waves x2, prefetch depth x3, LDS-DMA, nt stores, XCD swizzle; no pipe
// saturated (L1 15/64 B/cyc, L2 3/34.5 TB/s, HBM 2.5/6.3 TB/s, VALU 14%).
// Model: per-CU pending-miss cap (~64 line slots x ~700cyc RT = 0.09
// lines/cyc/CU -> 67us for 3.7M lines — matches R2). The never-removed
// suspect: each 16B group is requested ~4x by 4 separate overlapping window
// loads while the line is still in flight -> MSHR merge/replay pressure.
// R7 dedup'd via LDS-DMA but died on DMA-vs-ds_read port conflicts (9.3M cyc).
// R11 dedups in registers: 1 own-group load + 3-lane halo load -> ds_write_b128
// (exec-masked, safe) into wave-private double buffer -> 4x contiguous
// ds_read_b128 windows (bank-conflict-free). No barriers, no inline asm.
// R10 bug: halo source cols were buffer-index+4 (staged wseg+260 into the slot
// for wseg+256) -> absmax 1.49. Fixed: hcol = (wseg - 4 + hidx) & 2047.
constexpr int R    = 32;            // output rows per block
constexpr int NIT  = R + KS - 1;    // 41 streamed H-rows
constexpr int CPT  = 4;             // cols per thread
constexpr int BW   = 256 * CPT;     // 1024 cols per block
constexpr int WBUF = 272;           // floats per wave row buffer (268 used)

__device__ __constant__ float MTFf[C] = {0.38f, 0.34f, 0.34f, 0.26f, 0.22f, 0.23f};

template<int K> struct IC { static constexpr int v = K; };
template<int K, int N, typename F>
__device__ __forceinline__ void static_for(F&& f) {
    if constexpr (K < N) { f(IC<K>{}); static_for<K + 1, N>(f); }
}

__global__ __launch_bounds__(256, 3)   // 3 blocks/CU (grid 768); ~90 VGPR live, cap 168
void s2_blur_dedup(const float* __restrict__ x, float* __restrict__ out)
{
    // wave-private double-buffered row segments: [wave][buf][float]
    __shared__ __align__(16) float lds[4][2][WBUF];   // 8704 B

    const int t     = threadIdx.x;
    const int ln    = t & 63;
    const int wv    = t >> 6;
    const int c     = blockIdx.z;
    const int r0    = blockIdx.y * R;
    const int jt    = blockIdx.x * BW + t * CPT;     // first output col of this thread
    const int wseg  = blockIdx.x * BW + wv * 256;    // wave's 256-col segment start

    const float* xc = x   + (size_t)c * NR * NC;
    float*       oc = out + (size_t)c * NR * NC;

    // ---- per-thread fp32 weights (verified absmax 0.0039 << 0.0325) ----
    float w[KS];
    {
        float mtf    = MTFf[c];
        float sig    = 2.0f * sqrtf(-2.0f * logf(mtf) / (float)(M_PI * M_PI));
        float inv2s2 = 1.0f / (2.0f * sig * sig);
        float s = 0.0f;
        #pragma unroll
        for (int d = 0; d < KS; ++d) {
            float cd = -4.5f + (float)d;
            w[d] = expf(-cd * cd * inv2s2);
            s += w[d];
        }
        #pragma unroll
        for (int d = 0; d < KS; ++d) w[d] /= s;
    }

    // ---- addressing ----
    // Invariant: LDS buffer float i  <->  input col (wseg - 4 + i) & 2047.
    // Main load: lane ln owns cols [wseg+4ln, wseg+4ln+4) -> buffer [4+4ln, 8+4ln).
    //   wseg+4ln in [0, 2044]: never wraps.
    // Halo load (lanes 0..2), source col = (wseg - 4 + hidx) & 2047:
    //   ln0: hidx=0   -> cols wseg-4..wseg-1     -> buffer [0,4)
    //   ln1: hidx=260 -> cols wseg+256..wseg+259 -> buffer [260,264)
    //   ln2: hidx=264 -> cols wseg+260..wseg+263 -> buffer [264,268)
    //   (window max float index is 267; wraps are whole 4-float groups.)
    const int sMain = wseg + 4 * ln;
    const int hidx  = (ln == 1 ? 260 : (ln == 2 ? 264 : 0));
    const int hcol  = (wseg - 4 + hidx + NC) & (NC - 1);

    auto row_ptr = [&](int k) {
        return xc + (size_t)((r0 - PAD + k + NR) & (NR - 1)) * NC;
    };
    auto load_row = [&](int k, float4& m, float4& h) {
        const float* rp = row_ptr(k);
        m = *(const float4*)(rp + sMain);
        if (ln < 3) h = *(const float4*)(rp + hcol);
    };
    auto write_row = [&](int buf, const float4& m, const float4& h) {
        *(float4*)(&lds[wv][buf][4 + 4 * ln]) = m;
        if (ln < 3) *(float4*)(&lds[wv][buf][hidx]) = h;
    };

    // V-pass accumulator ring: slot m%10 holds strip-row m in flight
    float acc[KS][CPT] = {};

    // prologue: rows 0,1 loaded; row 0 staged into buf 0
    float4 mA = {}, hA = {}, mB = {}, hB = {};
    load_row(0, mA, hA);
    load_row(1, mB, hB);
    write_row(0, mA, hA);

    static_for<0, NIT>([&](auto ic) {
        constexpr int k = decltype(ic)::v;

        // 1. refill the reg slot freed when row k was staged last iter
        if constexpr (k + 2 < NIT) {
            if constexpr (k % 2 == 0) load_row(k + 2, mA, hA);
            else                      load_row(k + 2, mB, hB);
        }
        // 2. stage row k+1 into the other buffer (vmcnt slack: loaded 1 iter ago)
        if constexpr (k + 1 < NIT) {
            if constexpr ((k + 1) % 2 == 0) write_row((k + 1) & 1, mA, hA);
            else                            write_row((k + 1) & 1, mB, hB);
        }

        // 3. H-pass for row k from LDS: window = buffer floats [4ln, 4ln+16)
        //    (14 used). 4x ds_read_b128, contiguous per lane -> conflict-free.
        const float* lb = &lds[wv][k & 1][4 * ln];
        float4 a0 = *(const float4*)(lb + 0);
        float4 a1 = *(const float4*)(lb + 4);
        float4 a2 = *(const float4*)(lb + 8);
        float4 a3 = *(const float4*)(lb + 12);
        const float f[16] = {a0.x, a0.y, a0.z, a0.w,
                             a1.x, a1.y, a1.z, a1.w,
                             a2.x, a2.y, a2.z, a2.w,
                             a3.x, a3.y, a3.z, a3.w};
        float H[CPT];
        #pragma unroll
        for (int q = 0; q < CPT; ++q) {
            float a = 0.0f;
            #pragma unroll
            for (int d = 0; d < KS; ++d) a = fmaf(w[d], f[q + d], a);
            H[q] = a;
        }

        // 4. V-pass ring update: H row k feeds strip rows m = k-o, weight w[o]
        #pragma unroll
        for (int o = 0; o < KS; ++o) {
            const int m = k - o;
            if (m >= 0 && m < R) {
                const int s = m % KS;
                #pragma unroll
                for (int q = 0; q < CPT; ++q)
                    acc[s][q] = fmaf(w[o], H[q], acc[s][q]);
            }
        }

        // 5. emit finished strip row m = k-9
        if constexpr (k >= KS - 1) {
            constexpr int m  = k - (KS - 1);
            constexpr int sl = m % KS;
            float* orow = oc + (size_t)(r0 + m) * NC;   // wave-uniform base
            *(float4*)(orow + jt) = make_float4(acc[sl][0], acc[sl][1], acc[sl][2], acc[sl][3]);
            #pragma unroll
            for (int q = 0; q < CPT; ++q) acc[sl][q] = 0.0f;
        }
    });
}

extern "C" void kernel_launch(void* const* d_in, const int* in_sizes, int n_in,
                              void* d_out, int out_size, void* d_ws, size_t ws_size,
                              hipStream_t stream) {
    const float* x = (const float*)d_in[0];
    float* out = (float*)d_out;
    dim3 grid(NC / BW, NR / R, C);   // 2 x 64 x 6 = 768 blocks = 3 blocks/CU
    dim3 block(256);
    s2_blur_dedup<<<grid, block, 0, stream>>>(x, out);
}